// Round 12
// baseline (113.181 us; speedup 1.0000x reference)
//
#include <hip/hip_runtime.h>

#define NUM_CP 64
#define D_MODEL 128
#define RPB_MAX 4096   // max rows per block staged in LDS (16 KB)

typedef float f32x4 __attribute__((ext_vector_type(4)));

// Exact algebraic collapse of the reference for t in [0,1]:
//   out[n][d] = B[d] + clip(t[n],0,1) * C[d]
//   B[d] = sum_{i=0}^{62} (1 - i) * cp[i][d]
//   C[d] = -cp[0][d] + sum_{i=1}^{62} cp[i][d]
//
// R12: fill-kernel mimicry test. The 6.9 TB/s fillBufferAligned existence
// proof runs PLAIN stores at ~11% occupancy (~900 waves = few long store
// streams). All our 32-waves/CU variants pinned at 4.5 (plain) / 5.05 (NT)
// TB/s -> hypothesis: stream CONCURRENCY at the controllers is the limiter.
// This kernel: 256 blocks (4 waves/CU), plain stores, block-contiguous
// 1.95 MB output slabs. t-slab (15.6 KB) staged into LDS upfront per block
// (low occupancy can't hide load latency in the loop), steady loop = pure
// sequential plain-store stream, 1 KB contiguous per wave-store.
__global__ __launch_bounds__(256) void spline_fused(const float* __restrict__ t,
                                                    const float* __restrict__ cp,
                                                    float* __restrict__ out,
                                                    int n, int rpb) {
    __shared__ float sbc[2 * D_MODEL];
    __shared__ float st[RPB_MAX];

    const int tid = threadIdx.x;

    // ---- per-block coefficient reduction (threads 0-127, f32) ----
    if (tid < D_MODEL) {
        float v0 = cp[tid];            // cp[0][d]
        float B = v0, C = -v0;
        for (int i = 1; i < NUM_CP - 1; ++i) {
            float v = cp[i * D_MODEL + tid];
            B = fmaf(1.0f - (float)i, v, B);
            C += v;
        }
        sbc[tid] = B;
        sbc[D_MODEL + tid] = C;
    }

    // ---- stage this block's t slab into LDS (one coalesced burst) ----
    const int base = blockIdx.x * rpb;           // rpb % 8 == 0
    if (base >= n) return;
    const int cnt = min(rpb, n - base);
    {
        const f32x4* tq = reinterpret_cast<const f32x4*>(t + base);
        const int quads = cnt >> 2;
        for (int q = tid; q < quads; q += 256)
            reinterpret_cast<f32x4*>(st)[q] = tq[q];
        for (int r = (quads << 2) + tid; r < cnt; r += 256)
            st[r] = t[base + r];
    }
    __syncthreads();

    const int lane = tid & 63;
    const int c    = lane & 31;        // float4 column (0..31) -> dims 4c..4c+3
    const int half = lane >> 5;        // 0: even row of pair, 1: odd row
    const int wave = tid >> 6;

    const f32x4 b  = reinterpret_cast<const f32x4*>(sbc)[c];
    const f32x4 cv = reinterpret_cast<const f32x4*>(sbc + D_MODEL)[c];
    f32x4* __restrict__ outq = reinterpret_cast<f32x4*>(out) + (size_t)base * (D_MODEL / 4);

    // Steady loop: pure plain stores. Per 8-row chunk, store k covers the
    // consecutive row pair (r0+2k, r0+2k+1): lanes 0-31 -> even row (col c),
    // lanes 32-63 -> odd row  =>  lane l writes chunkbase + l*16 (1 KB contig).
    for (int r0 = wave * 8; r0 < cnt; r0 += 32) {
        if (r0 + 7 < cnt) {
            const f32x4 ta = reinterpret_cast<const f32x4*>(st)[(r0 >> 2)];
            const f32x4 tb = reinterpret_cast<const f32x4*>(st)[(r0 >> 2) + 1];
            float tv[4];
            tv[0] = half ? ta.y : ta.x;
            tv[1] = half ? ta.w : ta.z;
            tv[2] = half ? tb.y : tb.x;
            tv[3] = half ? tb.w : tb.z;
#pragma unroll
            for (int k = 0; k < 4; ++k) tv[k] = fminf(fmaxf(tv[k], 0.0f), 1.0f);
#pragma unroll
            for (int k = 0; k < 4; ++k) {
                f32x4 o;
                o.x = fmaf(tv[k], cv.x, b.x);
                o.y = fmaf(tv[k], cv.y, b.y);
                o.z = fmaf(tv[k], cv.z, b.z);
                o.w = fmaf(tv[k], cv.w, b.w);
                outq[(r0 + 2 * k + half) * 32 + c] = o;
            }
        } else {
            for (int k = 0; k < 4; ++k) {
                const int r = r0 + 2 * k + half;
                if (r < cnt) {
                    const float tv = fminf(fmaxf(st[r], 0.0f), 1.0f);
                    f32x4 o;
                    o.x = fmaf(tv, cv.x, b.x);
                    o.y = fmaf(tv, cv.y, b.y);
                    o.z = fmaf(tv, cv.z, b.z);
                    o.w = fmaf(tv, cv.w, b.w);
                    outq[r * 32 + c] = o;
                }
            }
        }
    }
}

extern "C" void kernel_launch(void* const* d_in, const int* in_sizes, int n_in,
                              void* d_out, int out_size, void* d_ws, size_t ws_size,
                              hipStream_t stream) {
    const float* t  = (const float*)d_in[0];
    const float* cp = (const float*)d_in[1];
    float* out = (float*)d_out;
    const int n = in_sizes[0];

    // ~256 blocks (1/CU, 4 waves/CU ~ fill kernel's occupancy), rows per
    // block rounded to x8 and capped by the LDS slab.
    int rpb = ((n + 256 * 8 - 1) / (256 * 8)) * 8;
    if (rpb > RPB_MAX) rpb = RPB_MAX;
    if (rpb < 8) rpb = 8;
    const int blocks = (n + rpb - 1) / rpb;
    spline_fused<<<blocks, 256, 0, stream>>>(t, cp, out, n, rpb);
}

// Round 13
// 110.553 us; speedup vs baseline: 1.0238x; 1.0238x over previous
//
#include <hip/hip_runtime.h>

#define NUM_CP 64
#define D_MODEL 128
#define RPB_MAX 4096   // max rows per block staged in LDS (16 KB)

typedef float f32x4 __attribute__((ext_vector_type(4)));

// Exact algebraic collapse of the reference for t in [0,1]:
//   out[n][d] = B[d] + clip(t[n],0,1) * C[d]
//   B[d] = sum_{i=0}^{62} (1 - i) * cp[i][d]
//   C[d] = -cp[0][d] + sum_{i=1}^{62} cp[i][d]
//
// R13: completes the {store-mode x occupancy} matrix — NT stores at LOW
// occupancy (4 waves/CU, 245 blocks, block-contiguous ~2 MB output slabs,
// t staged in LDS so the steady loop is a pure NT store stream, 1 KB
// contiguous per wave-store). Measured cells so far:
//   NT/high = 102.1 us | plain/high = 116.8 | plain/low = 113.2 | NT/low = ?
// If NT's controller-direct path is stream-concurrency-limited, this is
// the only remaining configuration that can approach the 6.9 TB/s fill
// proof point. Single-bit change vs R12 (plain -> NT).
__global__ __launch_bounds__(256) void spline_fused(const float* __restrict__ t,
                                                    const float* __restrict__ cp,
                                                    float* __restrict__ out,
                                                    int n, int rpb) {
    __shared__ float sbc[2 * D_MODEL];
    __shared__ float st[RPB_MAX];

    const int tid = threadIdx.x;

    // ---- per-block coefficient reduction (threads 0-127, f32) ----
    if (tid < D_MODEL) {
        float v0 = cp[tid];            // cp[0][d]
        float B = v0, C = -v0;
        for (int i = 1; i < NUM_CP - 1; ++i) {
            float v = cp[i * D_MODEL + tid];
            B = fmaf(1.0f - (float)i, v, B);
            C += v;
        }
        sbc[tid] = B;
        sbc[D_MODEL + tid] = C;
    }

    // ---- stage this block's t slab into LDS (one coalesced burst) ----
    const int base = blockIdx.x * rpb;           // rpb % 8 == 0
    if (base >= n) return;
    const int cnt = min(rpb, n - base);
    {
        const f32x4* tq = reinterpret_cast<const f32x4*>(t + base);
        const int quads = cnt >> 2;
        for (int q = tid; q < quads; q += 256)
            reinterpret_cast<f32x4*>(st)[q] = tq[q];
        for (int r = (quads << 2) + tid; r < cnt; r += 256)
            st[r] = t[base + r];
    }
    __syncthreads();

    const int lane = tid & 63;
    const int c    = lane & 31;        // float4 column (0..31) -> dims 4c..4c+3
    const int half = lane >> 5;        // 0: even row of pair, 1: odd row
    const int wave = tid >> 6;

    const f32x4 b  = reinterpret_cast<const f32x4*>(sbc)[c];
    const f32x4 cv = reinterpret_cast<const f32x4*>(sbc + D_MODEL)[c];
    f32x4* __restrict__ outq = reinterpret_cast<f32x4*>(out) + (size_t)base * (D_MODEL / 4);

    // Steady loop: pure NT stores. Per 8-row chunk, store k covers the
    // consecutive row pair (r0+2k, r0+2k+1): lanes 0-31 -> even row (col c),
    // lanes 32-63 -> odd row  =>  lane l writes chunkbase + l*16 (1 KB contig).
    for (int r0 = wave * 8; r0 < cnt; r0 += 32) {
        if (r0 + 7 < cnt) {
            const f32x4 ta = reinterpret_cast<const f32x4*>(st)[(r0 >> 2)];
            const f32x4 tb = reinterpret_cast<const f32x4*>(st)[(r0 >> 2) + 1];
            float tv[4];
            tv[0] = half ? ta.y : ta.x;
            tv[1] = half ? ta.w : ta.z;
            tv[2] = half ? tb.y : tb.x;
            tv[3] = half ? tb.w : tb.z;
#pragma unroll
            for (int k = 0; k < 4; ++k) tv[k] = fminf(fmaxf(tv[k], 0.0f), 1.0f);
#pragma unroll
            for (int k = 0; k < 4; ++k) {
                f32x4 o;
                o.x = fmaf(tv[k], cv.x, b.x);
                o.y = fmaf(tv[k], cv.y, b.y);
                o.z = fmaf(tv[k], cv.z, b.z);
                o.w = fmaf(tv[k], cv.w, b.w);
                __builtin_nontemporal_store(o, &outq[(r0 + 2 * k + half) * 32 + c]);
            }
        } else {
            for (int k = 0; k < 4; ++k) {
                const int r = r0 + 2 * k + half;
                if (r < cnt) {
                    const float tv = fminf(fmaxf(st[r], 0.0f), 1.0f);
                    f32x4 o;
                    o.x = fmaf(tv, cv.x, b.x);
                    o.y = fmaf(tv, cv.y, b.y);
                    o.z = fmaf(tv, cv.z, b.z);
                    o.w = fmaf(tv, cv.w, b.w);
                    __builtin_nontemporal_store(o, &outq[r * 32 + c]);
                }
            }
        }
    }
}

extern "C" void kernel_launch(void* const* d_in, const int* in_sizes, int n_in,
                              void* d_out, int out_size, void* d_ws, size_t ws_size,
                              hipStream_t stream) {
    const float* t  = (const float*)d_in[0];
    const float* cp = (const float*)d_in[1];
    float* out = (float*)d_out;
    const int n = in_sizes[0];

    // ~256 blocks (1/CU, 4 waves/CU ~ fill kernel's occupancy), rows per
    // block rounded to x8 and capped by the LDS slab.
    int rpb = ((n + 256 * 8 - 1) / (256 * 8)) * 8;
    if (rpb > RPB_MAX) rpb = RPB_MAX;
    if (rpb < 8) rpb = 8;
    const int blocks = (n + rpb - 1) / rpb;
    spline_fused<<<blocks, 256, 0, stream>>>(t, cp, out, n, rpb);
}

// Round 14
// 102.718 us; speedup vs baseline: 1.1019x; 1.0763x over previous
//
#include <hip/hip_runtime.h>

#define NUM_CP 64
#define D_MODEL 128

typedef float f32x4 __attribute__((ext_vector_type(4)));

// FINAL (revert to R9, the best-measured configuration: 102.1-102.2 us).
//
// Exact algebraic collapse of the reference for t in [0,1]:
//   out[n][d] = B[d] + clip(t[n],0,1) * C[d]
//   B[d] = sum_{i=0}^{62} (1 - i) * cp[i][d]
//   C[d] = -cp[0][d] + sum_{i=1}^{62} cp[i][d]
//
// Configuration knowledge from the R4-R13 A/B matrix:
//   - NT stores > plain (+14.5 us at high occ, +2.6 at low occ)
//   - high occupancy (32 w/CU) > low (4 w/CU) for NT (+8.5 us)
//   - neutral: t-load pipelining, LDS t-staging, store-segment shape,
//     per-wave write sequentiality -> 5.05 TB/s NT drain rate is invariant
//   - per-block f32 coeff prologue ~free; per-thread FP64 prologue = -13 us
__global__ __launch_bounds__(256) void spline_fused(const float* __restrict__ t,
                                                    const float* __restrict__ cp,
                                                    float* __restrict__ out, int n) {
    __shared__ float sbc[2 * D_MODEL];

    const int tid = threadIdx.x;
    if (tid < D_MODEL) {
        float v0 = cp[tid];            // cp[0][d]
        float B = v0, C = -v0;
        for (int i = 1; i < NUM_CP - 1; ++i) {
            float v = cp[i * D_MODEL + tid];
            B = fmaf(1.0f - (float)i, v, B);
            C += v;
        }
        sbc[tid] = B;
        sbc[D_MODEL + tid] = C;
    }
    __syncthreads();

    const int lane = tid & 63;
    const int c    = lane & 31;        // float4 column (0..31) -> dims 4c..4c+3
    const int half = lane >> 5;        // 0: even row of pair, 1: odd row

    const f32x4 b  = reinterpret_cast<const f32x4*>(sbc)[c];
    const f32x4 cv = reinterpret_cast<const f32x4*>(sbc + D_MODEL)[c];

    const int waveGlobal = blockIdx.x * 4 + (tid >> 6);
    const int nWaves     = gridDim.x * 4;
    const int rowStride  = nWaves * 8;
    f32x4* __restrict__ outq = reinterpret_cast<f32x4*>(out);

    int R0 = waveGlobal * 8;
    if (R0 >= n) return;

    bool full = (R0 + 7 < n);
    f32x4 ta, tb;                      // t[R0..R0+3], t[R0+4..R0+7] (broadcast)
    if (full) {
        ta = *reinterpret_cast<const f32x4*>(t + R0);
        tb = *reinterpret_cast<const f32x4*>(t + R0 + 4);
    }

    for (; R0 < n; R0 += rowStride) {
        const int R0n = R0 + rowStride;
        const bool fulln = (R0n + 7 < n);
        f32x4 tan_, tbn;
        if (fulln) {                   // prefetch next iter BEFORE stores
            tan_ = *reinterpret_cast<const f32x4*>(t + R0n);
            tbn  = *reinterpret_cast<const f32x4*>(t + R0n + 4);
        }

        if (full) {
            // this thread's rows: R0 + 2k + half, k = 0..3
            float tv[4];
            tv[0] = half ? ta.y : ta.x;
            tv[1] = half ? ta.w : ta.z;
            tv[2] = half ? tb.y : tb.x;
            tv[3] = half ? tb.w : tb.z;
#pragma unroll
            for (int k = 0; k < 4; ++k) tv[k] = fminf(fmaxf(tv[k], 0.0f), 1.0f);
#pragma unroll
            for (int k = 0; k < 4; ++k) {
                f32x4 o;
                o.x = fmaf(tv[k], cv.x, b.x);
                o.y = fmaf(tv[k], cv.y, b.y);
                o.z = fmaf(tv[k], cv.z, b.z);
                o.w = fmaf(tv[k], cv.w, b.w);
                // rows (R0+2k) and (R0+2k+1): lane l -> base + l*16, 1 KB contiguous
                __builtin_nontemporal_store(o, &outq[(R0 + 2 * k + half) * 32 + c]);
            }
        } else {
            for (int k = 0; k < 4; ++k) {
                const int r = R0 + 2 * k + half;
                if (r < n) {
                    float tv = fminf(fmaxf(t[r], 0.0f), 1.0f);
                    f32x4 o;
                    o.x = fmaf(tv, cv.x, b.x);
                    o.y = fmaf(tv, cv.y, b.y);
                    o.z = fmaf(tv, cv.z, b.z);
                    o.w = fmaf(tv, cv.w, b.w);
                    __builtin_nontemporal_store(o, &outq[r * 32 + c]);
                }
            }
        }
        ta = tan_;
        tb = tbn;
        full = fulln;
    }
}

extern "C" void kernel_launch(void* const* d_in, const int* in_sizes, int n_in,
                              void* d_out, int out_size, void* d_ws, size_t ws_size,
                              hipStream_t stream) {
    const float* t  = (const float*)d_in[0];
    const float* cp = (const float*)d_in[1];
    float* out = (float*)d_out;
    const int n = in_sizes[0];

    // 2048 blocks x 256 threads = 8 blocks/CU -> full 32-wave occupancy.
    const int waveTasks  = (n + 7) / 8;          // 8 rows per wave-iter
    const int wantBlocks = (waveTasks + 3) / 4;  // 4 waves per block
    const int blocks = wantBlocks < 2048 ? wantBlocks : 2048;
    spline_fused<<<blocks, 256, 0, stream>>>(t, cp, out, n);
}